// Round 1
// baseline (428.227 us; speedup 1.0000x reference)
//
#include <hip/hip_runtime.h>

typedef unsigned short u16;
typedef __attribute__((ext_vector_type(8))) short bf16x8;
typedef __attribute__((ext_vector_type(4))) float f32x4;

#define NN    10000
#define EE    160000
#define ET    170000      // EE + NN self loops
#define FIN   2000
#define MPAD  10112       // 79*128
#define K1PAD 2048
#define NH    1280        // heads*channels
#define HEADS 10

__device__ __forceinline__ u16 f32_to_bf16(float f) {
    unsigned u = __float_as_uint(f);
    unsigned r = (u + 0x7fffu + ((u >> 16) & 1u)) >> 16;
    return (u16)r;
}
__device__ __forceinline__ float bf16lo(unsigned pv) { return __uint_as_float(pv << 16); }
__device__ __forceinline__ float bf16hi(unsigned pv) { return __uint_as_float(pv & 0xffff0000u); }

__device__ __forceinline__ void gload16(const u16* g, u16* l) {
    __builtin_amdgcn_global_load_lds(
        (const __attribute__((address_space(1))) void*)g,
        (__attribute__((address_space(3))) void*)l, 16, 0, 0);
}

// ---------------- conversion kernels ----------------

// x [10000][2000] f32 -> A1 [10112][2048] bf16 (zero padded), packed 2 bf16/thread-iter
__global__ __launch_bounds__(256) void k_conv_x(const float* __restrict__ x,
                                                unsigned* __restrict__ A1) {
    const int total = MPAD * (K1PAD / 2);
    for (int idx = blockIdx.x * 256 + threadIdx.x; idx < total; idx += gridDim.x * 256) {
        int r = idx >> 10;            // /(K1PAD/2)
        int c = (idx & 1023) << 1;
        float v0 = 0.f, v1 = 0.f;
        if (r < NN && c < FIN) {      // FIN even -> c+1 also valid
            const float* xp = x + (size_t)r * FIN + c;
            v0 = xp[0]; v1 = xp[1];
        }
        A1[idx] = (unsigned)f32_to_bf16(v0) | ((unsigned)f32_to_bf16(v1) << 16);
    }
}

// W [K][Nn] f32 -> Bt [Nn][Kpad] bf16 (transpose + pad), LDS tiled
__global__ __launch_bounds__(256) void k_convT(const float* __restrict__ W,
                                               u16* __restrict__ Bt,
                                               int K, int Nn, int Kpad) {
    __shared__ float tile[32][33];
    int k0 = blockIdx.x * 32, n0 = blockIdx.y * 32;
    int tx = threadIdx.x, ty = threadIdx.y;   // (32,8)
    #pragma unroll
    for (int i = 0; i < 32; i += 8) {
        int k = k0 + ty + i;
        tile[ty + i][tx] = (k < K) ? W[(size_t)k * Nn + n0 + tx] : 0.f;
    }
    __syncthreads();
    #pragma unroll
    for (int i = 0; i < 32; i += 8) {
        int n = n0 + ty + i, k = k0 + tx;
        Bt[(size_t)n * Kpad + k] = f32_to_bf16(tile[tx][ty + i]);
    }
}

// ---------------- GEMM: C[M x 1280] = A[M x Kpad] * Bt[1280 x Kpad]^T, all bf16, fp32 acc ----
// 128x128 tile, BK=64, 4 waves, global_load_lds w/ inverse-swizzled source, XOR-swz ds_read

__global__ __launch_bounds__(256) void k_gemm(const u16* __restrict__ A,
                                              const u16* __restrict__ Bt,
                                              u16* __restrict__ C,
                                              const int Kpad, const int kTiles) {
    __shared__ __attribute__((aligned(16))) u16 As[8192];  // [128][64] linear
    __shared__ __attribute__((aligned(16))) u16 Bs[8192];
    const int t = threadIdx.x;
    const int lane = t & 63;
    const int wave = t >> 6;
    const int wr = wave >> 1, wc = wave & 1;
    const size_t m0 = (size_t)blockIdx.x * 128, n0 = (size_t)blockIdx.y * 128;

    f32x4 acc[4][4] = {};

    // staging: thread t loads 16B: row t>>3 (+32/inst), source col-block swizzled by row&7
    const int srow = t >> 3;
    const int scol = ((t & 7) ^ (srow & 7)) * 8;     // in elements
    const u16* aSrc = A + (m0 + srow) * (size_t)Kpad + scol;
    const u16* bSrc = Bt + (n0 + srow) * (size_t)Kpad + scol;
    u16* aDst = As + wave * 512;   // +lane*16B implicit
    u16* bDst = Bs + wave * 512;

    for (int kt = 0; kt < kTiles; ++kt) {
        const size_t ko = (size_t)kt * 64;
        #pragma unroll
        for (int i = 0; i < 4; ++i) {
            gload16(aSrc + ko + (size_t)i * 32 * Kpad, aDst + i * 2048);
            gload16(bSrc + ko + (size_t)i * 32 * Kpad, bDst + i * 2048);
        }
        __syncthreads();   // compiler drains vmcnt here
        #pragma unroll
        for (int ks = 0; ks < 2; ++ks) {
            bf16x8 af[4], bfr[4];
            const int kb = ks * 64 + ((lane >> 4) * 16);   // byte offset of k within row
            #pragma unroll
            for (int mf = 0; mf < 4; ++mf) {
                int row = wr * 64 + mf * 16 + (lane & 15);
                int bo = (row * 128 + kb) ^ ((row & 7) << 4);
                af[mf] = *(const bf16x8*)((const char*)As + bo);
            }
            #pragma unroll
            for (int nf = 0; nf < 4; ++nf) {
                int row = wc * 64 + nf * 16 + (lane & 15);
                int bo = (row * 128 + kb) ^ ((row & 7) << 4);
                bfr[nf] = *(const bf16x8*)((const char*)Bs + bo);
            }
            #pragma unroll
            for (int mf = 0; mf < 4; ++mf)
                #pragma unroll
                for (int nf = 0; nf < 4; ++nf)
                    acc[mf][nf] = __builtin_amdgcn_mfma_f32_16x16x32_bf16(
                        af[mf], bfr[nf], acc[mf][nf], 0, 0, 0);
        }
        __syncthreads();
    }
    // epilogue: C/D layout col=lane&15, row=(lane>>4)*4+i  (m89-verified)
    #pragma unroll
    for (int mf = 0; mf < 4; ++mf)
        #pragma unroll
        for (int i = 0; i < 4; ++i) {
            size_t row = m0 + wr * 64 + mf * 16 + (lane >> 4) * 4 + i;
            u16* crow = C + row * NH + n0 + wc * 64 + (lane & 15);
            #pragma unroll
            for (int nf = 0; nf < 4; ++nf)
                crow[nf * 16] = f32_to_bf16(acc[mf][nf][i]);
        }
}

// ---------------- attention coefficients: a_src/a_dst [10000][10] ----------------
__global__ __launch_bounds__(256) void k_attn(const u16* __restrict__ Hb,
                                              const float* __restrict__ att_s,
                                              const float* __restrict__ att_d,
                                              float* __restrict__ a_src,
                                              float* __restrict__ a_dst) {
    const int lane = threadIdx.x & 63;
    const int n = blockIdx.x * 4 + (threadIdx.x >> 6);
    if (n >= NN) return;
    const unsigned* hrow = (const unsigned*)(Hb + (size_t)n * NH) + lane;  // 2 ch / lane
    #pragma unroll
    for (int h = 0; h < HEADS; ++h) {
        unsigned pv = hrow[h * 64];
        float v0 = bf16lo(pv), v1 = bf16hi(pv);
        int c = h * 128 + lane * 2;
        float s = v0 * att_s[c] + v1 * att_s[c + 1];
        float d = v0 * att_d[c] + v1 * att_d[c + 1];
        #pragma unroll
        for (int o = 32; o; o >>= 1) { s += __shfl_xor(s, o); d += __shfl_xor(d, o); }
        if (lane == 0) { a_src[n * HEADS + h] = s; a_dst[n * HEADS + h] = d; }
    }
}

// ---------------- CSR build ----------------
__global__ void k_count(const int* __restrict__ ei, int* __restrict__ deg) {
    int e = blockIdx.x * blockDim.x + threadIdx.x;
    if (e >= ET) return;
    int d = (e < EE) ? ei[EE + e] : (e - EE);
    atomicAdd(&deg[d], 1);
}

__global__ __launch_bounds__(256) void k_scan(const int* __restrict__ deg,
                                              int* __restrict__ off,
                                              int* __restrict__ cursor) {
    // 256 threads, 40 elements each (250*40 = 10000)
    __shared__ int wt[4];
    const int t = threadIdx.x, lane = t & 63, w = t >> 6;
    const int lo = t * 40;
    const int hi = (lo + 40 < NN) ? lo + 40 : NN;
    int s = 0;
    for (int i = lo; i < hi; ++i) s += deg[i];
    int x = s;
    #pragma unroll
    for (int o = 1; o < 64; o <<= 1) { int y = __shfl_up(x, o); if (lane >= o) x += y; }
    if (lane == 63) wt[w] = x;
    __syncthreads();
    int wp = 0;
    for (int k = 0; k < w; ++k) wp += wt[k];
    int run = wp + x - s;     // exclusive prefix of this thread's chunk
    for (int i = lo; i < hi; ++i) { off[i] = run; cursor[i] = run; run += deg[i]; }
    if (t == 255) off[NN] = wp + x;
}

__global__ void k_scatter(const int* __restrict__ ei, int* __restrict__ cursor,
                          int* __restrict__ csr_src) {
    int e = blockIdx.x * blockDim.x + threadIdx.x;
    if (e >= ET) return;
    int s = (e < EE) ? ei[e] : (e - EE);
    int d = (e < EE) ? ei[EE + e] : (e - EE);
    int pos = atomicAdd(&cursor[d], 1);
    csr_src[pos] = s;
}

// ---------------- segment softmax + aggregate (one wave per dst node) ----------------
// LAYER 1: out = bf16( relu(agg + b1) )  -> A2 [.][1280]
// LAYER 2: out = f32 ( relu(mean_heads(agg) + b2) ) -> d_out [.][128]
template <int LAYER>
__global__ __launch_bounds__(256) void k_aggregate(const u16* __restrict__ Hb,
                                                   const float* __restrict__ a_src,
                                                   const float* __restrict__ a_dst,
                                                   const int* __restrict__ off,
                                                   const int* __restrict__ csr_src,
                                                   const float* __restrict__ bias,
                                                   void* __restrict__ outp) {
    const int lane = threadIdx.x & 63;
    const int n = blockIdx.x * 4 + (threadIdx.x >> 6);
    if (n >= NN) return;
    const int beg = off[n], end = off[n + 1];

    float adst[HEADS], mh[HEADS], sh[HEADS];
    #pragma unroll
    for (int h = 0; h < HEADS; ++h) {
        adst[h] = a_dst[n * HEADS + h]; mh[h] = -3e38f; sh[h] = 0.f;
    }
    // pass A: per-head max of leaky(logit)
    for (int i = beg + lane; i < end; i += 64) {
        const float* ap = a_src + (size_t)csr_src[i] * HEADS;
        #pragma unroll
        for (int h = 0; h < HEADS; ++h) {
            float e = ap[h] + adst[h]; e = (e >= 0.f) ? e : 0.2f * e;
            mh[h] = fmaxf(mh[h], e);
        }
    }
    #pragma unroll
    for (int h = 0; h < HEADS; ++h)
        #pragma unroll
        for (int o = 32; o; o >>= 1) mh[h] = fmaxf(mh[h], __shfl_xor(mh[h], o));
    // pass B: per-head sum of exp
    for (int i = beg + lane; i < end; i += 64) {
        const float* ap = a_src + (size_t)csr_src[i] * HEADS;
        #pragma unroll
        for (int h = 0; h < HEADS; ++h) {
            float e = ap[h] + adst[h]; e = (e >= 0.f) ? e : 0.2f * e;
            sh[h] += __expf(e - mh[h]);
        }
    }
    #pragma unroll
    for (int h = 0; h < HEADS; ++h) {
        #pragma unroll
        for (int o = 32; o; o >>= 1) sh[h] += __shfl_xor(sh[h], o);
        sh[h] = 1.f / (sh[h] + 1e-16f);
    }
    // pass C: alpha-weighted gather; lane owns channels {h*128 + lane*2, +1}
    float acc0[HEADS] = {}, acc1[HEADS] = {};
    for (int i = beg; i < end; ++i) {
        int s = csr_src[i];
        const float* ap = a_src + (size_t)s * HEADS;
        const unsigned* hrow = (const unsigned*)(Hb + (size_t)s * NH) + lane;
        #pragma unroll
        for (int h = 0; h < HEADS; ++h) {
            float e = ap[h] + adst[h]; e = (e >= 0.f) ? e : 0.2f * e;
            float al = __expf(e - mh[h]) * sh[h];
            unsigned pv = hrow[h * 64];
            acc0[h] = fmaf(bf16lo(pv), al, acc0[h]);
            acc1[h] = fmaf(bf16hi(pv), al, acc1[h]);
        }
    }
    if (LAYER == 1) {
        unsigned* orow = (unsigned*)outp + (size_t)n * 640 + lane;
        #pragma unroll
        for (int h = 0; h < HEADS; ++h) {
            int c = h * 128 + lane * 2;
            float v0 = acc0[h] + bias[c];     v0 = (v0 > 0.f) ? v0 : 0.f;
            float v1 = acc1[h] + bias[c + 1]; v1 = (v1 > 0.f) ? v1 : 0.f;
            orow[h * 64] = (unsigned)f32_to_bf16(v0) | ((unsigned)f32_to_bf16(v1) << 16);
        }
    } else {
        float m0 = 0.f, m1 = 0.f;
        #pragma unroll
        for (int h = 0; h < HEADS; ++h) { m0 += acc0[h]; m1 += acc1[h]; }
        float z0 = m0 * 0.1f + bias[lane * 2];     z0 = (z0 > 0.f) ? z0 : 0.f;
        float z1 = m1 * 0.1f + bias[lane * 2 + 1]; z1 = (z1 > 0.f) ? z1 : 0.f;
        float2* z = (float2*)((float*)outp + (size_t)n * 128 + lane * 2);
        *z = make_float2(z0, z1);
    }
}

// ---------------- host ----------------
extern "C" void kernel_launch(void* const* d_in, const int* in_sizes, int n_in,
                              void* d_out, int out_size, void* d_ws, size_t ws_size,
                              hipStream_t stream) {
    const float* x   = (const float*)d_in[0];
    const int*   ei  = (const int*)  d_in[1];
    const float* W1  = (const float*)d_in[2];
    const float* as1 = (const float*)d_in[3];
    const float* ad1 = (const float*)d_in[4];
    const float* b1  = (const float*)d_in[5];
    const float* W2  = (const float*)d_in[6];
    const float* as2 = (const float*)d_in[7];
    const float* ad2 = (const float*)d_in[8];
    const float* b2  = (const float*)d_in[9];

    char* ws = (char*)d_ws;
    // region 0: A1 [10112][2048]bf16; after gemm1 reused as A2 [10112][1280] + B2t [1280][1280]
    const size_t A1_OFF  = 0;
    const size_t A2_OFF  = 0;
    const size_t B2T_OFF = (size_t)MPAD * NH * 2;              // 25,886,720
    // region 1: h (layer1 then layer2) [10112][1280] bf16
    const size_t H_OFF   = (size_t)MPAD * K1PAD * 2;           // 41,418,752
    // region 2: B1t [1280][2048] bf16
    const size_t B1T_OFF = H_OFF + (size_t)MPAD * NH * 2;      // 67,305,472
    size_t o = B1T_OFF + (size_t)NH * K1PAD * 2;
    const size_t AS1_OFF = o; o += 400128;
    const size_t AD1_OFF = o; o += 400128;
    const size_t AS2_OFF = o; o += 400128;
    const size_t AD2_OFF = o; o += 400128;
    const size_t DEG_OFF = o; o += 40064;
    const size_t OFF_OFF = o; o += 40064;
    const size_t CUR_OFF = o; o += 40064;
    const size_t CSR_OFF = o; o += 680064;
    if (ws_size < o) return;   // insufficient workspace

    u16*   A1   = (u16*)(ws + A1_OFF);
    u16*   A2   = (u16*)(ws + A2_OFF);
    u16*   B2t  = (u16*)(ws + B2T_OFF);
    u16*   H    = (u16*)(ws + H_OFF);
    u16*   B1t  = (u16*)(ws + B1T_OFF);
    float* aS1  = (float*)(ws + AS1_OFF);
    float* aD1  = (float*)(ws + AD1_OFF);
    float* aS2  = (float*)(ws + AS2_OFF);
    float* aD2  = (float*)(ws + AD2_OFF);
    int*   deg  = (int*)(ws + DEG_OFF);
    int*   offp = (int*)(ws + OFF_OFF);
    int*   cur  = (int*)(ws + CUR_OFF);
    int*   csr  = (int*)(ws + CSR_OFF);

    // CSR build (independent of GEMM path)
    hipMemsetAsync(deg, 0, NN * sizeof(int), stream);
    k_count<<<(ET + 255) / 256, 256, 0, stream>>>(ei, deg);
    k_scan<<<1, 256, 0, stream>>>(deg, offp, cur);
    k_scatter<<<(ET + 255) / 256, 256, 0, stream>>>(ei, cur, csr);

    // layer 1
    k_conv_x<<<2048, 256, 0, stream>>>(x, (unsigned*)A1);
    k_convT<<<dim3(K1PAD / 32, NH / 32), dim3(32, 8), 0, stream>>>(W1, B1t, FIN, NH, K1PAD);
    k_gemm<<<dim3(MPAD / 128, NH / 128), 256, 0, stream>>>(A1, B1t, H, K1PAD, K1PAD / 64);
    k_attn<<<2500, 256, 0, stream>>>(H, as1, ad1, aS1, aD1);
    k_aggregate<1><<<2500, 256, 0, stream>>>(H, aS1, aD1, offp, csr, b1, A2);
    // zero A2 pad rows (rows 10000..10111) for gemm2
    hipMemsetAsync(A2 + (size_t)NN * NH, 0, (size_t)(MPAD - NN) * NH * 2, stream);

    // layer 2
    k_convT<<<dim3(NH / 32, NH / 32), dim3(32, 8), 0, stream>>>(W2, B2t, NH, NH, NH);
    k_gemm<<<dim3(MPAD / 128, NH / 128), 256, 0, stream>>>(A2, B2t, H, NH, NH / 64);
    k_attn<<<2500, 256, 0, stream>>>(H, as2, ad2, aS2, aD2);
    k_aggregate<2><<<2500, 256, 0, stream>>>(H, aS2, aD2, offp, csr, b2, d_out);
}

// Round 2
// 378.747 us; speedup vs baseline: 1.1306x; 1.1306x over previous
//
#include <hip/hip_runtime.h>

typedef unsigned short u16;
typedef __attribute__((ext_vector_type(8))) short bf16x8;
typedef __attribute__((ext_vector_type(4))) float f32x4;
typedef __attribute__((ext_vector_type(4))) unsigned u32x4;

#define NN    10000
#define EE    160000
#define ET    170000      // EE + NN self loops
#define FIN   2000
#define MPAD  10112       // 79*128
#define K1PAD 2048
#define NH    1280        // heads*channels
#define HEADS 10
#define NT    10          // N tiles (1280/128)
#define NWG   790         // 79*10 gemm workgroups

__device__ __forceinline__ u16 f32_to_bf16(float f) {
    unsigned u = __float_as_uint(f);
    unsigned r = (u + 0x7fffu + ((u >> 16) & 1u)) >> 16;
    return (u16)r;
}
__device__ __forceinline__ float bf16lo(unsigned pv) { return __uint_as_float(pv << 16); }
__device__ __forceinline__ float bf16hi(unsigned pv) { return __uint_as_float(pv & 0xffff0000u); }

__device__ __forceinline__ void gload16(const u16* g, u16* l) {
    __builtin_amdgcn_global_load_lds(
        (const __attribute__((address_space(1))) void*)g,
        (__attribute__((address_space(3))) void*)l, 16, 0, 0);
}

// ---------------- conversion kernels ----------------

__global__ __launch_bounds__(256) void k_conv_x(const float* __restrict__ x,
                                                unsigned* __restrict__ A1) {
    const int total = MPAD * (K1PAD / 2);
    for (int idx = blockIdx.x * 256 + threadIdx.x; idx < total; idx += gridDim.x * 256) {
        int r = idx >> 10;            // /(K1PAD/2)
        int c = (idx & 1023) << 1;
        float v0 = 0.f, v1 = 0.f;
        if (r < NN && c < FIN) {      // FIN even -> c+1 also valid
            const float* xp = x + (size_t)r * FIN + c;
            v0 = xp[0]; v1 = xp[1];
        }
        A1[idx] = (unsigned)f32_to_bf16(v0) | ((unsigned)f32_to_bf16(v1) << 16);
    }
}

__global__ __launch_bounds__(256) void k_convT(const float* __restrict__ W,
                                               u16* __restrict__ Bt,
                                               int K, int Nn, int Kpad) {
    __shared__ float tile[32][33];
    int k0 = blockIdx.x * 32, n0 = blockIdx.y * 32;
    int tx = threadIdx.x, ty = threadIdx.y;   // (32,8)
    #pragma unroll
    for (int i = 0; i < 32; i += 8) {
        int k = k0 + ty + i;
        tile[ty + i][tx] = (k < K) ? W[(size_t)k * Nn + n0 + tx] : 0.f;
    }
    __syncthreads();
    #pragma unroll
    for (int i = 0; i < 32; i += 8) {
        int n = n0 + ty + i, k = k0 + tx;
        Bt[(size_t)n * Kpad + k] = f32_to_bf16(tile[tx][ty + i]);
    }
}

// ---------------- GEMM: C[M x 1280] = A[M x Kpad] * Bt[1280 x Kpad]^T ----------------
// 128x128 tile, BK=64, 4 waves; XCD-bijective swizzle: each XCD owns a contiguous
// M-stripe x all N tiles (L2 working set per K-step ~320 KB).

__global__ __launch_bounds__(256) void k_gemm(const u16* __restrict__ A,
                                              const u16* __restrict__ Bt,
                                              u16* __restrict__ C,
                                              const int Kpad, const int kTiles) {
    __shared__ __attribute__((aligned(16))) u16 As[8192];  // [128][64] linear
    __shared__ __attribute__((aligned(16))) u16 Bs[8192];
    // bijective XCD swizzle (m204): xcd = bid%8 on HW; give each XCD a contiguous L-range
    const int bid = blockIdx.x;
    const int xcd = bid & 7, idx = bid >> 3;
    const int q = NWG >> 3, r = NWG & 7;
    const int L = (xcd < r) ? (xcd * (q + 1) + idx)
                            : (r * (q + 1) + (xcd - r) * q + idx);
    const size_t m0 = (size_t)(L / NT) * 128, n0 = (size_t)(L % NT) * 128;

    const int t = threadIdx.x;
    const int lane = t & 63;
    const int wave = t >> 6;
    const int wr = wave >> 1, wc = wave & 1;

    f32x4 acc[4][4] = {};

    const int srow = t >> 3;
    const int scol = ((t & 7) ^ (srow & 7)) * 8;     // inverse-swizzled source col
    const u16* aSrc = A + (m0 + srow) * (size_t)Kpad + scol;
    const u16* bSrc = Bt + (n0 + srow) * (size_t)Kpad + scol;
    u16* aDst = As + wave * 512;
    u16* bDst = Bs + wave * 512;

    for (int kt = 0; kt < kTiles; ++kt) {
        const size_t ko = (size_t)kt * 64;
        #pragma unroll
        for (int i = 0; i < 4; ++i) {
            gload16(aSrc + ko + (size_t)i * 32 * Kpad, aDst + i * 2048);
            gload16(bSrc + ko + (size_t)i * 32 * Kpad, bDst + i * 2048);
        }
        __syncthreads();
        #pragma unroll
        for (int ks = 0; ks < 2; ++ks) {
            bf16x8 af[4], bfr[4];
            const int kb = ks * 64 + ((lane >> 4) * 16);
            #pragma unroll
            for (int mf = 0; mf < 4; ++mf) {
                int row = wr * 64 + mf * 16 + (lane & 15);
                int bo = (row * 128 + kb) ^ ((row & 7) << 4);
                af[mf] = *(const bf16x8*)((const char*)As + bo);
            }
            #pragma unroll
            for (int nf = 0; nf < 4; ++nf) {
                int row = wc * 64 + nf * 16 + (lane & 15);
                int bo = (row * 128 + kb) ^ ((row & 7) << 4);
                bfr[nf] = *(const bf16x8*)((const char*)Bs + bo);
            }
            #pragma unroll
            for (int mf = 0; mf < 4; ++mf)
                #pragma unroll
                for (int nf = 0; nf < 4; ++nf)
                    acc[mf][nf] = __builtin_amdgcn_mfma_f32_16x16x32_bf16(
                        af[mf], bfr[nf], acc[mf][nf], 0, 0, 0);
        }
        __syncthreads();
    }
    #pragma unroll
    for (int mf = 0; mf < 4; ++mf)
        #pragma unroll
        for (int i = 0; i < 4; ++i) {
            size_t row = m0 + wr * 64 + mf * 16 + (lane >> 4) * 4 + i;
            u16* crow = C + row * NH + n0 + wc * 64 + (lane & 15);
            #pragma unroll
            for (int nf = 0; nf < 4; ++nf)
                crow[nf * 16] = f32_to_bf16(acc[mf][nf][i]);
        }
}

// ---------------- attention coefficients: a_src/a_dst [10000][10] ----------------
__global__ __launch_bounds__(256) void k_attn(const u16* __restrict__ Hb,
                                              const float* __restrict__ att_s,
                                              const float* __restrict__ att_d,
                                              float* __restrict__ a_src,
                                              float* __restrict__ a_dst) {
    const int lane = threadIdx.x & 63;
    const int n = blockIdx.x * 4 + (threadIdx.x >> 6);
    if (n >= NN) return;
    const unsigned* hrow = (const unsigned*)(Hb + (size_t)n * NH) + lane;  // 2 ch / lane
    #pragma unroll
    for (int h = 0; h < HEADS; ++h) {
        unsigned pv = hrow[h * 64];
        float v0 = bf16lo(pv), v1 = bf16hi(pv);
        int c = h * 128 + lane * 2;
        float s = v0 * att_s[c] + v1 * att_s[c + 1];
        float d = v0 * att_d[c] + v1 * att_d[c + 1];
        #pragma unroll
        for (int o = 32; o; o >>= 1) { s += __shfl_xor(s, o); d += __shfl_xor(d, o); }
        if (lane == 0) { a_src[n * HEADS + h] = s; a_dst[n * HEADS + h] = d; }
    }
}

// ---------------- CSR build ----------------
__global__ void k_count(const int* __restrict__ ei, int* __restrict__ deg) {
    int e = blockIdx.x * blockDim.x + threadIdx.x;
    if (e >= ET) return;
    int d = (e < EE) ? ei[EE + e] : (e - EE);
    atomicAdd(&deg[d], 1);
}

__global__ __launch_bounds__(256) void k_scan(const int* __restrict__ deg,
                                              int* __restrict__ off,
                                              int* __restrict__ cursor) {
    __shared__ int wt[4];
    const int t = threadIdx.x, lane = t & 63, w = t >> 6;
    const int lo = t * 40;
    const int hi = (lo + 40 < NN) ? lo + 40 : NN;
    int s = 0;
    for (int i = lo; i < hi; ++i) s += deg[i];
    int x = s;
    #pragma unroll
    for (int o = 1; o < 64; o <<= 1) { int y = __shfl_up(x, o); if (lane >= o) x += y; }
    if (lane == 63) wt[w] = x;
    __syncthreads();
    int wp = 0;
    for (int k = 0; k < w; ++k) wp += wt[k];
    int run = wp + x - s;
    for (int i = lo; i < hi; ++i) { off[i] = run; cursor[i] = run; run += deg[i]; }
    if (t == 255) off[NN] = wp + x;
}

__global__ void k_scatter(const int* __restrict__ ei, int* __restrict__ cursor,
                          int* __restrict__ csr_src) {
    int e = blockIdx.x * blockDim.x + threadIdx.x;
    if (e >= ET) return;
    int s = (e < EE) ? ei[e] : (e - EE);
    int d = (e < EE) ? ei[EE + e] : (e - EE);
    int pos = atomicAdd(&cursor[d], 1);
    csr_src[pos] = s;
}

// ---------------- fused single-pass segment softmax + aggregate ----------------
// No max-subtraction (|logit| <~ 10, exp is f32-safe; softmax is shift-invariant).
// Accumulate num = sum exp(e)*h and den = sum exp(e) in ONE edge pass.
// Lane owns 8 contiguous channels at offset ko=(lane&15)*8 in heads {g, g+4, g+8(g<2)}.
// LAYER 1: out = bf16(relu(num/den + b1)) -> A2 [n][1280]
// LAYER 2: out = f32 (relu(mean_h(num/den) + b2)) -> d_out [n][128]
template <int LAYER>
__global__ __launch_bounds__(256) void k_aggregate(const u16* __restrict__ Hb,
                                                   const float* __restrict__ a_src,
                                                   const float* __restrict__ a_dst,
                                                   const int* __restrict__ off,
                                                   const int* __restrict__ csr_src,
                                                   const float* __restrict__ bias,
                                                   void* __restrict__ outp) {
    const int lane = threadIdx.x & 63;
    const int n = blockIdx.x * 4 + (threadIdx.x >> 6);
    if (n >= NN) return;
    const int beg = off[n], end = off[n + 1];
    const int g = lane >> 4;
    const int ko = (lane & 15) * 8;
    const bool hasC = (g < 2);
    const int hA = g, hB = 4 + g, hC = 8 + g;   // hC valid iff hasC
    const float* adp = a_dst + (size_t)n * HEADS;
    const float dA = adp[hA], dB = adp[hB];
    const float dC = hasC ? adp[hC] : 0.f;

    float accA[8] = {}, accB[8] = {}, accC[8] = {};
    float denA = 0.f, denB = 0.f, denC = 0.f;

    for (int i = beg; i < end; ++i) {
        const int s = csr_src[i];
        const float* ap = a_src + (size_t)s * HEADS;
        const u16* hrow = Hb + (size_t)s * NH;
        float eA = ap[hA] + dA; eA = (eA >= 0.f) ? eA : 0.2f * eA;
        float eB = ap[hB] + dB; eB = (eB >= 0.f) ? eB : 0.2f * eB;
        const float wA = __expf(eA), wB = __expf(eB);
        denA += wA; denB += wB;
        const u32x4 vA = *(const u32x4*)(hrow + hA * 128 + ko);
        const u32x4 vB = *(const u32x4*)(hrow + hB * 128 + ko);
        #pragma unroll
        for (int j = 0; j < 4; ++j) {
            accA[2 * j]     = fmaf(bf16lo(vA[j]), wA, accA[2 * j]);
            accA[2 * j + 1] = fmaf(bf16hi(vA[j]), wA, accA[2 * j + 1]);
            accB[2 * j]     = fmaf(bf16lo(vB[j]), wB, accB[2 * j]);
            accB[2 * j + 1] = fmaf(bf16hi(vB[j]), wB, accB[2 * j + 1]);
        }
        if (hasC) {
            float eC = ap[hC] + dC; eC = (eC >= 0.f) ? eC : 0.2f * eC;
            const float wC = __expf(eC);
            denC += wC;
            const u32x4 vC = *(const u32x4*)(hrow + hC * 128 + ko);
            #pragma unroll
            for (int j = 0; j < 4; ++j) {
                accC[2 * j]     = fmaf(bf16lo(vC[j]), wC, accC[2 * j]);
                accC[2 * j + 1] = fmaf(bf16hi(vC[j]), wC, accC[2 * j + 1]);
            }
        }
    }
    const float siA = 1.f / (denA + 1e-16f);
    const float siB = 1.f / (denB + 1e-16f);
    const float siC = 1.f / (denC + 1e-16f);   // g>=2: accC==0 -> contributes 0

    if (LAYER == 1) {
        u16* orow = (u16*)outp + (size_t)n * NH;
        u32x4 pA, pB, pC;
        #pragma unroll
        for (int j = 0; j < 4; ++j) {
            float a0 = fmaxf(fmaf(accA[2 * j], siA, bias[hA * 128 + ko + 2 * j]), 0.f);
            float a1 = fmaxf(fmaf(accA[2 * j + 1], siA, bias[hA * 128 + ko + 2 * j + 1]), 0.f);
            pA[j] = (unsigned)f32_to_bf16(a0) | ((unsigned)f32_to_bf16(a1) << 16);
            float b0 = fmaxf(fmaf(accB[2 * j], siB, bias[hB * 128 + ko + 2 * j]), 0.f);
            float b1v = fmaxf(fmaf(accB[2 * j + 1], siB, bias[hB * 128 + ko + 2 * j + 1]), 0.f);
            pB[j] = (unsigned)f32_to_bf16(b0) | ((unsigned)f32_to_bf16(b1v) << 16);
        }
        *(u32x4*)(orow + hA * 128 + ko) = pA;
        *(u32x4*)(orow + hB * 128 + ko) = pB;
        if (hasC) {
            #pragma unroll
            for (int j = 0; j < 4; ++j) {
                float c0 = fmaxf(fmaf(accC[2 * j], siC, bias[hC * 128 + ko + 2 * j]), 0.f);
                float c1 = fmaxf(fmaf(accC[2 * j + 1], siC, bias[hC * 128 + ko + 2 * j + 1]), 0.f);
                pC[j] = (unsigned)f32_to_bf16(c0) | ((unsigned)f32_to_bf16(c1) << 16);
            }
            *(u32x4*)(orow + hC * 128 + ko) = pC;
        }
    } else {
        // per-lane partial head-sum over its heads; channel c=ko+j partials live on
        // lanes {k, k+16, k+32, k+48} -> butterfly over bits 4,5
        float p[8];
        #pragma unroll
        for (int j = 0; j < 8; ++j)
            p[j] = accA[j] * siA + accB[j] * siB + accC[j] * siC;
        #pragma unroll
        for (int j = 0; j < 8; ++j) {
            p[j] += __shfl_xor(p[j], 16);
            p[j] += __shfl_xor(p[j], 32);
        }
        if (g == 0) {
            float* orow = (float*)outp + (size_t)n * 128 + ko;
            f32x4 z0, z1;
            #pragma unroll
            for (int j = 0; j < 4; ++j) {
                z0[j] = fmaxf(fmaf(p[j], 0.1f, bias[ko + j]), 0.f);
                z1[j] = fmaxf(fmaf(p[4 + j], 0.1f, bias[ko + 4 + j]), 0.f);
            }
            *(f32x4*)orow = z0;
            *(f32x4*)(orow + 4) = z1;
        }
    }
}

// ---------------- host ----------------
extern "C" void kernel_launch(void* const* d_in, const int* in_sizes, int n_in,
                              void* d_out, int out_size, void* d_ws, size_t ws_size,
                              hipStream_t stream) {
    const float* x   = (const float*)d_in[0];
    const int*   ei  = (const int*)  d_in[1];
    const float* W1  = (const float*)d_in[2];
    const float* as1 = (const float*)d_in[3];
    const float* ad1 = (const float*)d_in[4];
    const float* b1  = (const float*)d_in[5];
    const float* W2  = (const float*)d_in[6];
    const float* as2 = (const float*)d_in[7];
    const float* ad2 = (const float*)d_in[8];
    const float* b2  = (const float*)d_in[9];

    char* ws = (char*)d_ws;
    const size_t A1_OFF  = 0;
    const size_t A2_OFF  = 0;
    const size_t B2T_OFF = (size_t)MPAD * NH * 2;
    const size_t H_OFF   = (size_t)MPAD * K1PAD * 2;
    const size_t B1T_OFF = H_OFF + (size_t)MPAD * NH * 2;
    size_t o = B1T_OFF + (size_t)NH * K1PAD * 2;
    const size_t AS1_OFF = o; o += 400128;
    const size_t AD1_OFF = o; o += 400128;
    const size_t AS2_OFF = o; o += 400128;
    const size_t AD2_OFF = o; o += 400128;
    const size_t DEG_OFF = o; o += 40064;
    const size_t OFF_OFF = o; o += 40064;
    const size_t CUR_OFF = o; o += 40064;
    const size_t CSR_OFF = o; o += 680064;
    if (ws_size < o) return;

    u16*   A1   = (u16*)(ws + A1_OFF);
    u16*   A2   = (u16*)(ws + A2_OFF);
    u16*   B2t  = (u16*)(ws + B2T_OFF);
    u16*   H    = (u16*)(ws + H_OFF);
    u16*   B1t  = (u16*)(ws + B1T_OFF);
    float* aS1  = (float*)(ws + AS1_OFF);
    float* aD1  = (float*)(ws + AD1_OFF);
    float* aS2  = (float*)(ws + AS2_OFF);
    float* aD2  = (float*)(ws + AD2_OFF);
    int*   deg  = (int*)(ws + DEG_OFF);
    int*   offp = (int*)(ws + OFF_OFF);
    int*   cur  = (int*)(ws + CUR_OFF);
    int*   csr  = (int*)(ws + CSR_OFF);

    // CSR build
    hipMemsetAsync(deg, 0, NN * sizeof(int), stream);
    k_count<<<(ET + 255) / 256, 256, 0, stream>>>(ei, deg);
    k_scan<<<1, 256, 0, stream>>>(deg, offp, cur);
    k_scatter<<<(ET + 255) / 256, 256, 0, stream>>>(ei, cur, csr);

    // layer 1
    k_conv_x<<<2048, 256, 0, stream>>>(x, (unsigned*)A1);
    k_convT<<<dim3(K1PAD / 32, NH / 32), dim3(32, 8), 0, stream>>>(W1, B1t, FIN, NH, K1PAD);
    k_gemm<<<NWG, 256, 0, stream>>>(A1, B1t, H, K1PAD, K1PAD / 64);
    k_attn<<<2500, 256, 0, stream>>>(H, as1, ad1, aS1, aD1);
    k_aggregate<1><<<2500, 256, 0, stream>>>(H, aS1, aD1, offp, csr, b1, A2);
    hipMemsetAsync(A2 + (size_t)NN * NH, 0, (size_t)(MPAD - NN) * NH * 2, stream);

    // layer 2
    k_convT<<<dim3(NH / 32, NH / 32), dim3(32, 8), 0, stream>>>(W2, B2t, NH, NH, NH);
    k_gemm<<<NWG, 256, 0, stream>>>(A2, B2t, H, NH, NH / 64);
    k_attn<<<2500, 256, 0, stream>>>(H, as2, ad2, aS2, aD2);
    k_aggregate<2><<<2500, 256, 0, stream>>>(H, aS2, aD2, offp, csr, b2, d_out);
}

// Round 3
// 345.391 us; speedup vs baseline: 1.2398x; 1.0966x over previous
//
#include <hip/hip_runtime.h>

typedef unsigned short u16;
typedef __attribute__((ext_vector_type(8))) short bf16x8;
typedef __attribute__((ext_vector_type(4))) float f32x4;
typedef __attribute__((ext_vector_type(4))) unsigned u32x4;

#define NN    10000
#define EE    160000
#define ET    170000      // EE + NN self loops
#define FIN   2000
#define MPAD  10112       // 79*128
#define K1PAD 2048
#define NH    1280        // heads*channels
#define HEADS 10
#define NT    10          // N tiles (1280/128)
#define NWG   790         // 79*10 gemm workgroups

__device__ __forceinline__ u16 f32_to_bf16(float f) {
    unsigned u = __float_as_uint(f);
    unsigned r = (u + 0x7fffu + ((u >> 16) & 1u)) >> 16;
    return (u16)r;
}
__device__ __forceinline__ float bf16lo(unsigned pv) { return __uint_as_float(pv << 16); }
__device__ __forceinline__ float bf16hi(unsigned pv) { return __uint_as_float(pv & 0xffff0000u); }

__device__ __forceinline__ void gload16(const u16* g, u16* l) {
    __builtin_amdgcn_global_load_lds(
        (const __attribute__((address_space(1))) void*)g,
        (__attribute__((address_space(3))) void*)l, 16, 0, 0);
}

// ---------------- conversion kernels ----------------

// x [10000][2000] f32 -> A1 [10112][2048] bf16 (zero padded), float4 loads
__global__ __launch_bounds__(256) void k_conv_x(const float* __restrict__ x,
                                                uint2* __restrict__ A1) {
    const int total = MPAD * (K1PAD / 4);
    for (int idx = blockIdx.x * 256 + threadIdx.x; idx < total; idx += gridDim.x * 256) {
        int r = idx >> 9;             // /(K1PAD/4)
        int c = (idx & 511) << 2;
        float4 v = make_float4(0.f, 0.f, 0.f, 0.f);
        if (r < NN && c < FIN) {      // FIN%4==0 -> full vec valid
            v = *(const float4*)(x + (size_t)r * FIN + c);
        }
        uint2 p;
        p.x = (unsigned)f32_to_bf16(v.x) | ((unsigned)f32_to_bf16(v.y) << 16);
        p.y = (unsigned)f32_to_bf16(v.z) | ((unsigned)f32_to_bf16(v.w) << 16);
        A1[idx] = p;
    }
}

__global__ __launch_bounds__(256) void k_convT(const float* __restrict__ W,
                                               u16* __restrict__ Bt,
                                               int K, int Nn, int Kpad) {
    __shared__ float tile[32][33];
    int k0 = blockIdx.x * 32, n0 = blockIdx.y * 32;
    int tx = threadIdx.x, ty = threadIdx.y;   // (32,8)
    #pragma unroll
    for (int i = 0; i < 32; i += 8) {
        int k = k0 + ty + i;
        tile[ty + i][tx] = (k < K) ? W[(size_t)k * Nn + n0 + tx] : 0.f;
    }
    __syncthreads();
    #pragma unroll
    for (int i = 0; i < 32; i += 8) {
        int n = n0 + ty + i, k = k0 + tx;
        Bt[(size_t)n * Kpad + k] = f32_to_bf16(tile[tx][ty + i]);
    }
}

// ---------------- GEMM: C[M x 1280] = A[M x Kpad] * Bt[1280 x Kpad]^T ----------------
// 128x128 tile, BK=64, 4 waves; XCD-bijective swizzle; double-buffered LDS with
// raw s_barrier + explicit vmcnt so next-tile staging flies under current compute.

__global__ __launch_bounds__(256) void k_gemm(const u16* __restrict__ A,
                                              const u16* __restrict__ Bt,
                                              u16* __restrict__ C,
                                              const int Kpad, const int kTiles) {
    // layout (u16 units): A0 @0, B0 @8192, A1 @16384, B1 @24576  (each [128][64] linear)
    __shared__ __attribute__((aligned(16))) u16 S[32768];
    const int bid = blockIdx.x;
    const int xcd = bid & 7, idx = bid >> 3;
    const int q = NWG >> 3, r = NWG & 7;
    const int L = (xcd < r) ? (xcd * (q + 1) + idx)
                            : (r * (q + 1) + (xcd - r) * q + idx);
    const size_t m0 = (size_t)(L / NT) * 128, n0 = (size_t)(L % NT) * 128;

    const int t = threadIdx.x;
    const int lane = t & 63;
    const int wave = t >> 6;
    const int wr = wave >> 1, wc = wave & 1;

    f32x4 acc[4][4] = {};

    const int srow = t >> 3;
    const int scol = ((t & 7) ^ (srow & 7)) * 8;     // inverse-swizzled source col
    const u16* aSrc = A + (m0 + srow) * (size_t)Kpad + scol;
    const u16* bSrc = Bt + (n0 + srow) * (size_t)Kpad + scol;

#define STAGE(kt_, buf_) do {                                                  \
        const size_t ko_ = (size_t)(kt_) * 64;                                 \
        u16* aD = S + (buf_) * 16384 + wave * 512;                             \
        u16* bD = S + (buf_) * 16384 + 8192 + wave * 512;                      \
        _Pragma("unroll")                                                      \
        for (int i_ = 0; i_ < 4; ++i_) {                                       \
            gload16(aSrc + ko_ + (size_t)i_ * 32 * Kpad, aD + i_ * 2048);      \
            gload16(bSrc + ko_ + (size_t)i_ * 32 * Kpad, bD + i_ * 2048);      \
        }                                                                      \
    } while (0)

    STAGE(0, 0);   // prologue

    const char* Sb = (const char*)S;
    for (int kt = 0; kt < kTiles; ++kt) {
        asm volatile("s_waitcnt vmcnt(0)" ::: "memory");  // this tile's stage landed
        __builtin_amdgcn_s_barrier();                     // all waves agree; prev reads done
        if (kt + 1 < kTiles) STAGE(kt + 1, (kt + 1) & 1); // prefetch flies under compute
        const int bufo = (kt & 1) * 32768;                // byte offset of current buffer
        #pragma unroll
        for (int ks = 0; ks < 2; ++ks) {
            bf16x8 af[4], bfr[4];
            const int kb = ks * 64 + ((lane >> 4) * 16);
            #pragma unroll
            for (int mf = 0; mf < 4; ++mf) {
                int row = wr * 64 + mf * 16 + (lane & 15);
                int bo = bufo + ((row * 128 + kb) ^ ((row & 7) << 4));
                af[mf] = *(const bf16x8*)(Sb + bo);
            }
            #pragma unroll
            for (int nf = 0; nf < 4; ++nf) {
                int row = wc * 64 + nf * 16 + (lane & 15);
                int bo = bufo + 16384 + ((row * 128 + kb) ^ ((row & 7) << 4));
                bfr[nf] = *(const bf16x8*)(Sb + bo);
            }
            #pragma unroll
            for (int mf = 0; mf < 4; ++mf)
                #pragma unroll
                for (int nf = 0; nf < 4; ++nf)
                    acc[mf][nf] = __builtin_amdgcn_mfma_f32_16x16x32_bf16(
                        af[mf], bfr[nf], acc[mf][nf], 0, 0, 0);
        }
    }
#undef STAGE

    #pragma unroll
    for (int mf = 0; mf < 4; ++mf)
        #pragma unroll
        for (int i = 0; i < 4; ++i) {
            size_t row = m0 + wr * 64 + mf * 16 + (lane >> 4) * 4 + i;
            u16* crow = C + row * NH + n0 + wc * 64 + (lane & 15);
            #pragma unroll
            for (int nf = 0; nf < 4; ++nf)
                crow[nf * 16] = f32_to_bf16(acc[mf][nf][i]);
        }
}

// ---------------- attention coefficients: a_src/a_dst [10000][10] ----------------
__global__ __launch_bounds__(256) void k_attn(const u16* __restrict__ Hb,
                                              const float* __restrict__ att_s,
                                              const float* __restrict__ att_d,
                                              float* __restrict__ a_src,
                                              float* __restrict__ a_dst) {
    const int lane = threadIdx.x & 63;
    const int n = blockIdx.x * 4 + (threadIdx.x >> 6);
    if (n >= NN) return;
    const unsigned* hrow = (const unsigned*)(Hb + (size_t)n * NH) + lane;  // 2 ch / lane
    #pragma unroll
    for (int h = 0; h < HEADS; ++h) {
        unsigned pv = hrow[h * 64];
        float v0 = bf16lo(pv), v1 = bf16hi(pv);
        int c = h * 128 + lane * 2;
        float s = v0 * att_s[c] + v1 * att_s[c + 1];
        float d = v0 * att_d[c] + v1 * att_d[c + 1];
        #pragma unroll
        for (int o = 32; o; o >>= 1) { s += __shfl_xor(s, o); d += __shfl_xor(d, o); }
        if (lane == 0) { a_src[n * HEADS + h] = s; a_dst[n * HEADS + h] = d; }
    }
}

// ---------------- CSR build ----------------
__global__ void k_count(const int* __restrict__ ei, int* __restrict__ deg) {
    int e = blockIdx.x * blockDim.x + threadIdx.x;
    if (e >= ET) return;
    int d = (e < EE) ? ei[EE + e] : (e - EE);
    atomicAdd(&deg[d], 1);
}

__global__ __launch_bounds__(256) void k_scan(const int* __restrict__ deg,
                                              int* __restrict__ off,
                                              int* __restrict__ cursor) {
    __shared__ int wt[4];
    const int t = threadIdx.x, lane = t & 63, w = t >> 6;
    const int lo = t * 40;
    const int hi = (lo + 40 < NN) ? lo + 40 : NN;
    int s = 0;
    for (int i = lo; i < hi; ++i) s += deg[i];
    int x = s;
    #pragma unroll
    for (int o = 1; o < 64; o <<= 1) { int y = __shfl_up(x, o); if (lane >= o) x += y; }
    if (lane == 63) wt[w] = x;
    __syncthreads();
    int wp = 0;
    for (int k = 0; k < w; ++k) wp += wt[k];
    int run = wp + x - s;
    for (int i = lo; i < hi; ++i) { off[i] = run; cursor[i] = run; run += deg[i]; }
    if (t == 255) off[NN] = wp + x;
}

__global__ void k_scatter(const int* __restrict__ ei, int* __restrict__ cursor,
                          int* __restrict__ csr_src) {
    int e = blockIdx.x * blockDim.x + threadIdx.x;
    if (e >= ET) return;
    int s = (e < EE) ? ei[e] : (e - EE);
    int d = (e < EE) ? ei[EE + e] : (e - EE);
    int pos = atomicAdd(&cursor[d], 1);
    csr_src[pos] = s;
}

// ---------------- fused single-pass segment softmax + aggregate ----------------
template <int LAYER>
__global__ __launch_bounds__(256) void k_aggregate(const u16* __restrict__ Hb,
                                                   const float* __restrict__ a_src,
                                                   const float* __restrict__ a_dst,
                                                   const int* __restrict__ off,
                                                   const int* __restrict__ csr_src,
                                                   const float* __restrict__ bias,
                                                   void* __restrict__ outp) {
    const int lane = threadIdx.x & 63;
    const int n = blockIdx.x * 4 + (threadIdx.x >> 6);
    if (n >= NN) return;
    const int beg = off[n], end = off[n + 1];
    const int g = lane >> 4;
    const int ko = (lane & 15) * 8;
    const bool hasC = (g < 2);
    const int hA = g, hB = 4 + g, hC = 8 + g;   // hC valid iff hasC
    const float* adp = a_dst + (size_t)n * HEADS;
    const float dA = adp[hA], dB = adp[hB];
    const float dC = hasC ? adp[hC] : 0.f;

    float accA[8] = {}, accB[8] = {}, accC[8] = {};
    float denA = 0.f, denB = 0.f, denC = 0.f;

    for (int i = beg; i < end; ++i) {
        const int s = csr_src[i];
        const float* ap = a_src + (size_t)s * HEADS;
        const u16* hrow = Hb + (size_t)s * NH;
        float eA = ap[hA] + dA; eA = (eA >= 0.f) ? eA : 0.2f * eA;
        float eB = ap[hB] + dB; eB = (eB >= 0.f) ? eB : 0.2f * eB;
        const float wA = __expf(eA), wB = __expf(eB);
        denA += wA; denB += wB;
        const u32x4 vA = *(const u32x4*)(hrow + hA * 128 + ko);
        const u32x4 vB = *(const u32x4*)(hrow + hB * 128 + ko);
        #pragma unroll
        for (int j = 0; j < 4; ++j) {
            accA[2 * j]     = fmaf(bf16lo(vA[j]), wA, accA[2 * j]);
            accA[2 * j + 1] = fmaf(bf16hi(vA[j]), wA, accA[2 * j + 1]);
            accB[2 * j]     = fmaf(bf16lo(vB[j]), wB, accB[2 * j]);
            accB[2 * j + 1] = fmaf(bf16hi(vB[j]), wB, accB[2 * j + 1]);
        }
        if (hasC) {
            float eC = ap[hC] + dC; eC = (eC >= 0.f) ? eC : 0.2f * eC;
            const float wC = __expf(eC);
            denC += wC;
            const u32x4 vC = *(const u32x4*)(hrow + hC * 128 + ko);
            #pragma unroll
            for (int j = 0; j < 4; ++j) {
                accC[2 * j]     = fmaf(bf16lo(vC[j]), wC, accC[2 * j]);
                accC[2 * j + 1] = fmaf(bf16hi(vC[j]), wC, accC[2 * j + 1]);
            }
        }
    }
    const float siA = 1.f / (denA + 1e-16f);
    const float siB = 1.f / (denB + 1e-16f);
    const float siC = 1.f / (denC + 1e-16f);

    if (LAYER == 1) {
        u16* orow = (u16*)outp + (size_t)n * NH;
        u32x4 pA, pB, pC;
        #pragma unroll
        for (int j = 0; j < 4; ++j) {
            float a0 = fmaxf(fmaf(accA[2 * j], siA, bias[hA * 128 + ko + 2 * j]), 0.f);
            float a1 = fmaxf(fmaf(accA[2 * j + 1], siA, bias[hA * 128 + ko + 2 * j + 1]), 0.f);
            pA[j] = (unsigned)f32_to_bf16(a0) | ((unsigned)f32_to_bf16(a1) << 16);
            float b0 = fmaxf(fmaf(accB[2 * j], siB, bias[hB * 128 + ko + 2 * j]), 0.f);
            float b1v = fmaxf(fmaf(accB[2 * j + 1], siB, bias[hB * 128 + ko + 2 * j + 1]), 0.f);
            pB[j] = (unsigned)f32_to_bf16(b0) | ((unsigned)f32_to_bf16(b1v) << 16);
        }
        *(u32x4*)(orow + hA * 128 + ko) = pA;
        *(u32x4*)(orow + hB * 128 + ko) = pB;
        if (hasC) {
            #pragma unroll
            for (int j = 0; j < 4; ++j) {
                float c0 = fmaxf(fmaf(accC[2 * j], siC, bias[hC * 128 + ko + 2 * j]), 0.f);
                float c1 = fmaxf(fmaf(accC[2 * j + 1], siC, bias[hC * 128 + ko + 2 * j + 1]), 0.f);
                pC[j] = (unsigned)f32_to_bf16(c0) | ((unsigned)f32_to_bf16(c1) << 16);
            }
            *(u32x4*)(orow + hC * 128 + ko) = pC;
        }
    } else {
        float p[8];
        #pragma unroll
        for (int j = 0; j < 8; ++j)
            p[j] = accA[j] * siA + accB[j] * siB + accC[j] * siC;
        #pragma unroll
        for (int j = 0; j < 8; ++j) {
            p[j] += __shfl_xor(p[j], 16);
            p[j] += __shfl_xor(p[j], 32);
        }
        if (g == 0) {
            float* orow = (float*)outp + (size_t)n * 128 + ko;
            f32x4 z0, z1;
            #pragma unroll
            for (int j = 0; j < 4; ++j) {
                z0[j] = fmaxf(fmaf(p[j], 0.1f, bias[ko + j]), 0.f);
                z1[j] = fmaxf(fmaf(p[4 + j], 0.1f, bias[ko + 4 + j]), 0.f);
            }
            *(f32x4*)orow = z0;
            *(f32x4*)(orow + 4) = z1;
        }
    }
}

// ---------------- host ----------------
extern "C" void kernel_launch(void* const* d_in, const int* in_sizes, int n_in,
                              void* d_out, int out_size, void* d_ws, size_t ws_size,
                              hipStream_t stream) {
    const float* x   = (const float*)d_in[0];
    const int*   ei  = (const int*)  d_in[1];
    const float* W1  = (const float*)d_in[2];
    const float* as1 = (const float*)d_in[3];
    const float* ad1 = (const float*)d_in[4];
    const float* b1  = (const float*)d_in[5];
    const float* W2  = (const float*)d_in[6];
    const float* as2 = (const float*)d_in[7];
    const float* ad2 = (const float*)d_in[8];
    const float* b2  = (const float*)d_in[9];

    char* ws = (char*)d_ws;
    const size_t A1_OFF  = 0;
    const size_t A2_OFF  = 0;
    const size_t B2T_OFF = (size_t)MPAD * NH * 2;
    const size_t H_OFF   = (size_t)MPAD * K1PAD * 2;
    const size_t B1T_OFF = H_OFF + (size_t)MPAD * NH * 2;
    size_t o = B1T_OFF + (size_t)NH * K1PAD * 2;
    const size_t AS1_OFF = o; o += 400128;
    const size_t AD1_OFF = o; o += 400128;
    const size_t AS2_OFF = o; o += 400128;
    const size_t AD2_OFF = o; o += 400128;
    const size_t DEG_OFF = o; o += 40064;
    const size_t OFF_OFF = o; o += 40064;
    const size_t CUR_OFF = o; o += 40064;
    const size_t CSR_OFF = o; o += 680064;
    if (ws_size < o) return;

    u16*   A1   = (u16*)(ws + A1_OFF);
    u16*   A2   = (u16*)(ws + A2_OFF);
    u16*   B2t  = (u16*)(ws + B2T_OFF);
    u16*   H    = (u16*)(ws + H_OFF);
    u16*   B1t  = (u16*)(ws + B1T_OFF);
    float* aS1  = (float*)(ws + AS1_OFF);
    float* aD1  = (float*)(ws + AD1_OFF);
    float* aS2  = (float*)(ws + AS2_OFF);
    float* aD2  = (float*)(ws + AD2_OFF);
    int*   deg  = (int*)(ws + DEG_OFF);
    int*   offp = (int*)(ws + OFF_OFF);
    int*   cur  = (int*)(ws + CUR_OFF);
    int*   csr  = (int*)(ws + CSR_OFF);

    // CSR build
    hipMemsetAsync(deg, 0, NN * sizeof(int), stream);
    k_count<<<(ET + 255) / 256, 256, 0, stream>>>(ei, deg);
    k_scan<<<1, 256, 0, stream>>>(deg, offp, cur);
    k_scatter<<<(ET + 255) / 256, 256, 0, stream>>>(ei, cur, csr);

    // layer 1
    k_conv_x<<<2048, 256, 0, stream>>>(x, (uint2*)A1);
    k_convT<<<dim3(K1PAD / 32, NH / 32), dim3(32, 8), 0, stream>>>(W1, B1t, FIN, NH, K1PAD);
    k_gemm<<<NWG, 256, 0, stream>>>(A1, B1t, H, K1PAD, K1PAD / 64);
    k_attn<<<2500, 256, 0, stream>>>(H, as1, ad1, aS1, aD1);
    k_aggregate<1><<<2500, 256, 0, stream>>>(H, aS1, aD1, offp, csr, b1, A2);
    hipMemsetAsync(A2 + (size_t)NN * NH, 0, (size_t)(MPAD - NN) * NH * 2, stream);

    // layer 2
    k_convT<<<dim3(NH / 32, NH / 32), dim3(32, 8), 0, stream>>>(W2, B2t, NH, NH, NH);
    k_gemm<<<NWG, 256, 0, stream>>>(A2, B2t, H, NH, NH / 64);
    k_attn<<<2500, 256, 0, stream>>>(H, as2, ad2, aS2, aD2);
    k_aggregate<2><<<2500, 256, 0, stream>>>(H, aS2, aD2, offp, csr, b2, d_out);
}